// Round 3
// baseline (124.699 us; speedup 1.0000x reference)
//
#include <hip/hip_runtime.h>
#include <math.h>

// FrequencyAdaptiveNorm: multi-scale (w=5,10,20) centered sliding-window
// normalization over L, softmax-weighted fusion.
// x: (B=32, L=2048, F=256) f32, weights: (3,) f32, out: same as x.
//
// v3: float2 per thread (f-pair) + fully-unrolled register delay line +
// interior/edge specialization (interior chunks: no bounds checks at all).
// Each thread owns 2 f-columns over a TL=32 chunk of L. One float2 load and
// one float2 store per iteration; ring shift is register renaming under full
// unroll.

#define B_ 32
#define L_ 2048
#define F_ 256
#define TL 32            // L-chunk per (thread y-slice)
#define NC 2             // columns (f) per thread

__device__ __forceinline__ float fin(float v) {
    return isfinite(v) ? v : 0.0f;   // nan_to_num(nan=0, +inf=0, -inf=0)
}

__global__ __launch_bounds__(256, 4)
void fan_kernel(const float* __restrict__ x,
                const float* __restrict__ w,
                float* __restrict__ out) {
    const int f0 = threadIdx.x * NC;                     // 0,2,..,254
    const int b  = blockIdx.y;
    const int l0 = (blockIdx.x * blockDim.y + threadIdx.y) * TL;
    const float* xb = x   + (size_t)b * L_ * F_ + f0;
    float*       ob = out + (size_t)b * L_ * F_ + f0;

    // softmax over the 3 fusion logits (uniform)
    const float w0 = w[0], w1 = w[1], w2 = w[2];
    const float m  = fmaxf(w0, fmaxf(w1, w2));
    const float e0 = expf(w0 - m), e1 = expf(w1 - m), e2 = expf(w2 - m);
    const float inv = 1.0f / (e0 + e1 + e2);
    const float ws5 = e0 * inv, ws10 = e1 * inv, ws20 = e2 * inv;
    const float eps = 1e-5f;

    // state: delay line ring[c][d] = x[l0-10+d, f0+c], running sums per scale
    float ring[NC][21];
    float s5[NC], q5[NC], s10[NC], q10[NC], s20[NC], q20[NC];

    const bool interior = (l0 >= 32) && (l0 <= L_ - TL - 11);

    if (interior) {
        // ---------- interior: no bounds checks anywhere ----------
#pragma unroll
        for (int d = 0; d < 21; ++d) {
            const float2 v = *reinterpret_cast<const float2*>(xb + (l0 - 10 + d) * F_);
            ring[0][d] = fin(v.x);
            ring[1][d] = fin(v.y);
        }
#pragma unroll
        for (int c = 0; c < NC; ++c) {
            s5[c] = q5[c] = s10[c] = q10[c] = s20[c] = q20[c] = 0.f;
#pragma unroll
            for (int d = 0; d < 20; ++d) { s20[c] += ring[c][d]; q20[c] += ring[c][d] * ring[c][d]; }
#pragma unroll
            for (int d = 5; d < 15; ++d) { s10[c] += ring[c][d]; q10[c] += ring[c][d] * ring[c][d]; }
#pragma unroll
            for (int d = 8; d < 13; ++d) { s5[c]  += ring[c][d]; q5[c]  += ring[c][d] * ring[c][d]; }
        }

#pragma unroll
        for (int t = 0; t < TL; ++t) {
            const int j = l0 + t;
            const float2 vn = *reinterpret_cast<const float2*>(xb + (j + 11) * F_);
            const float vnew[NC] = { fin(vn.x), fin(vn.y) };

            float2 o;
            float* op = &o.x;
#pragma unroll
            for (int c = 0; c < NC; ++c) {
                const float xc = ring[c][10];
                float acc;
                {   // w=5
                    const float mean = s5[c] * 0.2f;
                    const float var  = fmaxf(q5[c] * 0.2f - mean * mean, 0.0f);
                    acc = ws5 * (xc - mean) * rsqrtf(var + eps);
                }
                {   // w=10
                    const float mean = s10[c] * 0.1f;
                    const float var  = fmaxf(q10[c] * 0.1f - mean * mean, 0.0f);
                    acc += ws10 * (xc - mean) * rsqrtf(var + eps);
                }
                {   // w=20
                    const float mean = s20[c] * 0.05f;
                    const float var  = fmaxf(q20[c] * 0.05f - mean * mean, 0.0f);
                    acc += ws20 * (xc - mean) * rsqrtf(var + eps);
                }
                op[c] = acc;

                // slide windows j -> j+1
                const float a5  = ring[c][13], r5  = ring[c][8];
                s5[c]  += a5  - r5;  q5[c]  += a5 * a5   - r5 * r5;
                const float a10 = ring[c][15], r10 = ring[c][5];
                s10[c] += a10 - r10; q10[c] += a10 * a10 - r10 * r10;
                const float a20 = ring[c][20], r20 = ring[c][0];
                s20[c] += a20 - r20; q20[c] += a20 * a20 - r20 * r20;

                // shift delay line (register renaming under full unroll)
#pragma unroll
                for (int d = 0; d < 20; ++d) ring[c][d] = ring[c][d + 1];
                ring[c][20] = vnew[c];
            }
            *reinterpret_cast<float2*>(ob + j * F_) = o;
        }
    } else {
        // ---------- edge: checked path (2 of 64 chunks) ----------
#pragma unroll
        for (int d = 0; d < 21; ++d) {
            const int l = l0 - 10 + d;
            float2 v = make_float2(0.f, 0.f);
            if ((unsigned)l < (unsigned)L_)
                v = *reinterpret_cast<const float2*>(xb + l * F_);
            ring[0][d] = fin(v.x);
            ring[1][d] = fin(v.y);
        }
#pragma unroll
        for (int c = 0; c < NC; ++c) {
            s5[c] = q5[c] = s10[c] = q10[c] = s20[c] = q20[c] = 0.f;
#pragma unroll
            for (int d = 0; d < 20; ++d) { s20[c] += ring[c][d]; q20[c] += ring[c][d] * ring[c][d]; }
#pragma unroll
            for (int d = 5; d < 15; ++d) { s10[c] += ring[c][d]; q10[c] += ring[c][d] * ring[c][d]; }
#pragma unroll
            for (int d = 8; d < 13; ++d) { s5[c]  += ring[c][d]; q5[c]  += ring[c][d] * ring[c][d]; }
        }

        for (int t = 0; t < TL; ++t) {
            const int j = l0 + t;
            const int ln = j + 11;
            float2 vn = make_float2(0.f, 0.f);
            if ((unsigned)ln < (unsigned)L_)
                vn = *reinterpret_cast<const float2*>(xb + ln * F_);
            const float vnew[NC] = { fin(vn.x), fin(vn.y) };

            const bool v5  = (j >= 2)  && (j <= L_ - 3);
            const bool v10 = (j >= 5)  && (j <= L_ - 5);
            const bool v20 = (j >= 10) && (j <= L_ - 10);

            float2 o;
            float* op = &o.x;
#pragma unroll
            for (int c = 0; c < NC; ++c) {
                const float xc = ring[c][10];
                float acc = 0.f;
                if (v5) {
                    const float mean = s5[c] * 0.2f;
                    const float var  = fmaxf(q5[c] * 0.2f - mean * mean, 0.0f);
                    acc += ws5 * (xc - mean) * rsqrtf(var + eps);
                }
                if (v10) {
                    const float mean = s10[c] * 0.1f;
                    const float var  = fmaxf(q10[c] * 0.1f - mean * mean, 0.0f);
                    acc += ws10 * (xc - mean) * rsqrtf(var + eps);
                }
                if (v20) {
                    const float mean = s20[c] * 0.05f;
                    const float var  = fmaxf(q20[c] * 0.05f - mean * mean, 0.0f);
                    acc += ws20 * (xc - mean) * rsqrtf(var + eps);
                }
                op[c] = acc;

                const float a5  = ring[c][13], r5  = ring[c][8];
                s5[c]  += a5  - r5;  q5[c]  += a5 * a5   - r5 * r5;
                const float a10 = ring[c][15], r10 = ring[c][5];
                s10[c] += a10 - r10; q10[c] += a10 * a10 - r10 * r10;
                const float a20 = ring[c][20], r20 = ring[c][0];
                s20[c] += a20 - r20; q20[c] += a20 * a20 - r20 * r20;

#pragma unroll
                for (int d = 0; d < 20; ++d) ring[c][d] = ring[c][d + 1];
                ring[c][20] = vnew[c];
            }
            *reinterpret_cast<float2*>(ob + j * F_) = o;
        }
    }
}

extern "C" void kernel_launch(void* const* d_in, const int* in_sizes, int n_in,
                              void* d_out, int out_size, void* d_ws, size_t ws_size,
                              hipStream_t stream) {
    const float* x = (const float*)d_in[0];
    const float* w = (const float*)d_in[1];
    float* out = (float*)d_out;
    (void)in_sizes; (void)n_in; (void)out_size; (void)d_ws; (void)ws_size;

    // block: 128 threads span f (float2 each) x 2 L-chunks = 256 threads
    dim3 block(F_ / NC, 2);
    // grid: 32 x-chunks of 2*TL rows, 32 batches -> 1024 blocks = 4096 waves
    dim3 grid(L_ / (TL * 2), B_);
    hipLaunchKernelGGL(fan_kernel, grid, block, 0, stream, x, w, out);
}

// Round 4
// 34.783 us; speedup vs baseline: 3.5850x; 3.5850x over previous
//
#include <hip/hip_runtime.h>
#include <math.h>

// FrequencyAdaptiveNorm: multi-scale (w=5,10,20) centered sliding-window
// normalization over L, softmax-weighted fusion.
// x: (B=32, L=2048, F=256) f32, weights: (3,) f32, out: same shape.
//
// v4: v2 skeleton (scalar register delay line, one thread per f-column per
// TL=32 L-chunk) + full inner-loop unroll (ring shift -> SSA renaming) +
// block-uniform interior/edge specialization + fma-fused slide/norm math.
// No local arrays with non-static indexing, no address-taken locals (v3's
// scratch-spill lesson).

#define B_ 32
#define L_ 2048
#define F_ 256
#define TL 32   // L-chunk per block; grid = (64, 32) = 2048 blocks

__device__ __forceinline__ float fin(float v) {
    return isfinite(v) ? v : 0.0f;   // nan_to_num(nan=0, +inf=0, -inf=0)
}

template <bool CHECKED>
__device__ __forceinline__ void run_chunk(const float* __restrict__ xb,
                                          float* __restrict__ ob,
                                          const int l0,
                                          const float ws5, const float ws10,
                                          const float ws20) {
    const float eps = 1e-5f;

    // delay line: ring[d] = x[l0-10+d], d = 0..20
    float ring[21];
#pragma unroll
    for (int d = 0; d < 21; ++d) {
        const int l = l0 - 10 + d;
        float v;
        if (CHECKED)
            v = ((unsigned)l < (unsigned)L_) ? xb[l * F_] : 0.0f;
        else
            v = xb[l * F_];
        ring[d] = fin(v);
    }

    // running sums at j=l0: w5=ring[8..12], w10=ring[5..14], w20=ring[0..19]
    float s5 = 0.f, q5 = 0.f, s10 = 0.f, q10 = 0.f, s20 = 0.f, q20 = 0.f;
#pragma unroll
    for (int d = 0; d < 20; ++d) { s20 += ring[d]; q20 = fmaf(ring[d], ring[d], q20); }
#pragma unroll
    for (int d = 5; d < 15; ++d) { s10 += ring[d]; q10 = fmaf(ring[d], ring[d], q10); }
#pragma unroll
    for (int d = 8; d < 13; ++d) { s5  += ring[d]; q5  = fmaf(ring[d], ring[d], q5);  }

#pragma unroll
    for (int t = 0; t < TL; ++t) {
        const int j = l0 + t;

        // prefetch next ring element (independent of loop-carried sums)
        float vnew;
        if (CHECKED) {
            const int ln = j + 11;
            vnew = ((unsigned)ln < (unsigned)L_) ? fin(xb[ln * F_]) : 0.0f;
        } else {
            vnew = fin(xb[(j + 11) * F_]);
        }

        const float xc = ring[10];
        float acc = 0.0f;

        if (!CHECKED || (j >= 2 && j <= L_ - 3)) {          // w=5
            const float mean  = s5 * 0.2f;
            const float mean2 = q5 * 0.2f;
            const float var   = fmaxf(fmaf(-mean, mean, mean2), 0.0f);
            acc = fmaf(ws5, (xc - mean) * rsqrtf(var + eps), acc);
        }
        if (!CHECKED || (j >= 5 && j <= L_ - 5)) {          // w=10
            const float mean  = s10 * 0.1f;
            const float mean2 = q10 * 0.1f;
            const float var   = fmaxf(fmaf(-mean, mean, mean2), 0.0f);
            acc = fmaf(ws10, (xc - mean) * rsqrtf(var + eps), acc);
        }
        if (!CHECKED || (j >= 10 && j <= L_ - 10)) {        // w=20
            const float mean  = s20 * 0.05f;
            const float mean2 = q20 * 0.05f;
            const float var   = fmaxf(fmaf(-mean, mean, mean2), 0.0f);
            acc = fmaf(ws20, (xc - mean) * rsqrtf(var + eps), acc);
        }
        ob[j * F_] = acc;

        // slide windows j -> j+1:  s += a-r;  q += (a-r)(a+r)
        {
            const float a = ring[13], r = ring[8];
            const float d = a - r, p = a + r;
            s5 += d; q5 = fmaf(d, p, q5);
        }
        {
            const float a = ring[15], r = ring[5];
            const float d = a - r, p = a + r;
            s10 += d; q10 = fmaf(d, p, q10);
        }
        {
            const float a = ring[20], r = ring[0];
            const float d = a - r, p = a + r;
            s20 += d; q20 = fmaf(d, p, q20);
        }

        // shift delay line — full unroll makes this pure register renaming
#pragma unroll
        for (int d = 0; d < 20; ++d) ring[d] = ring[d + 1];
        ring[20] = vnew;
    }
}

__global__ __launch_bounds__(256, 8)
void fan_kernel(const float* __restrict__ x,
                const float* __restrict__ w,
                float* __restrict__ out) {
    const int f  = threadIdx.x;           // 0..255 == F
    const int b  = blockIdx.y;
    const int l0 = blockIdx.x * TL;
    const float* xb = x   + (size_t)b * L_ * F_ + f;
    float*       ob = out + (size_t)b * L_ * F_ + f;

    // softmax over the 3 fusion logits (uniform across threads)
    const float w0 = w[0], w1 = w[1], w2 = w[2];
    const float m  = fmaxf(w0, fmaxf(w1, w2));
    const float e0 = expf(w0 - m), e1 = expf(w1 - m), e2 = expf(w2 - m);
    const float inv = 1.0f / (e0 + e1 + e2);
    const float ws5 = e0 * inv, ws10 = e1 * inv, ws20 = e2 * inv;

    // interior blocks: all loads l0-10..l0+TL+10 in range AND all three
    // window validity ranges cover every j in the chunk.
    if (blockIdx.x != 0 && blockIdx.x != gridDim.x - 1)
        run_chunk<false>(xb, ob, l0, ws5, ws10, ws20);
    else
        run_chunk<true>(xb, ob, l0, ws5, ws10, ws20);
}

extern "C" void kernel_launch(void* const* d_in, const int* in_sizes, int n_in,
                              void* d_out, int out_size, void* d_ws, size_t ws_size,
                              hipStream_t stream) {
    const float* x = (const float*)d_in[0];
    const float* w = (const float*)d_in[1];
    float* out = (float*)d_out;
    (void)in_sizes; (void)n_in; (void)out_size; (void)d_ws; (void)ws_size;

    dim3 grid(L_ / TL, B_);   // (64, 32) = 2048 blocks
    dim3 block(F_);           // 256 threads, one per feature column
    hipLaunchKernelGGL(fan_kernel, grid, block, 0, stream, x, w, out);
}